// Round 6
// baseline (7284.563 us; speedup 1.0000x reference)
//
#include <hip/hip_runtime.h>
#include <hip/hip_bf16.h>
#include <cstdint>
#include <cstddef>

// LSTM_3624952398014 — R6: counter-published LLC exchange (no tags, no poll
// storm). R5's XCD-local path deadlocked (sc0-only visibility not guaranteed
// across the blocks that poll) — reverted to the proven device-coherent LLC
// path, but detection is now a single per-(rg,step) counter:
//   writer wave: h stores (sc0 sc1 write-through) -> vmcnt(0) -> lane0
//     atomicAdd(cnt[rg][t+1]) (device-scope RMW at the coherence point).
//   reader: spin on ONE dword until cnt==128, then load the 16KB h data
//     exactly once (sc0 sc1). Stores reached LLC before the RMW, so
//     counter==128 proves the data loads see fresh values.
// This kills R4's 4MB-per-round poll re-reads (self-congestion) and halves
// the exchanged bytes (no tag per word).
// Layer 1 of the reference is dead code; out = relu(h_final(L0)) @ W_out^T + b.

#define B_ 64
#define T_ 2048
#define F_ 128
#define H_ 512

#define NBLK 128
#define NTHR 256

#define ACT_STRIDE 1280                 // 640 bf16 per act row
#define SMEM_SZ (16 * ACT_STRIDE)       // 20480 B
// hbuf: [2 slots][64 rows][512 j] bf16 = 131072 B
// cnt:  [4 rg][4096] u32; cnt[rg][t] counts waves that published h_t (max 128)

typedef __bf16 bf16;
typedef __bf16 bf16x4 __attribute__((ext_vector_type(4)));
typedef __bf16 bf16x8 __attribute__((ext_vector_type(8)));
typedef float f32x4 __attribute__((ext_vector_type(4)));
typedef unsigned int u32;
typedef u32 u32x4 __attribute__((ext_vector_type(4)));

static __device__ __forceinline__ float sigm(float v) {
  return 1.f / (1.f + __expf(-v));
}
static __device__ __forceinline__ float tanh_f(float v) {
  float a = fminf(fabsf(v), 20.f);
  float e = __expf(-2.f * a);
  float t = 1.f - 2.f * e / (1.f + e);
  return copysignf(t, v);
}
static __device__ __forceinline__ u32 bf16bits(float f) {
  bf16 b = (bf16)f;
  unsigned short us;
  __builtin_memcpy(&us, &b, 2);
  return (u32)us;
}

__global__ void __launch_bounds__(NTHR) prep_kernel(u32* hbuf_words, u32* cnt) {
  int idx = blockIdx.x * blockDim.x + threadIdx.x;   // 128*256 = 32768
  hbuf_words[idx] = 0u;                              // both slots -> h0 = 0
  if (idx < 16384) cnt[idx] = ((idx & 4095) == 0) ? 128u : 0u;  // seed t=0
}

// x [B][T][F] f32  ->  xbf [T][4 rg][16 row][128] bf16
__global__ void __launch_bounds__(NTHR) xconv_kernel(
    const float* __restrict__ x, bf16* __restrict__ xbf) {
  const int b = blockIdx.x;          // 0..63
  const int t0 = blockIdx.y * 256;   // grid.y = 8
  const int f2 = threadIdx.x & 63;   // 2 floats per thread
  const int tq = threadIdx.x >> 6;   // 0..3
  const int rg = b >> 4, row = b & 15;
  for (int i = 0; i < 64; ++i) {
    int t = t0 + i * 4 + tq;
    float2 xv = *(const float2*)(x + ((size_t)b * T_ + t) * F_ + 2 * f2);
    u32 w = bf16bits(xv.x) | (bf16bits(xv.y) << 16);
    *(u32*)((char*)xbf + ((((size_t)t * 4 + rg) * 16 + row) * 128 + 2 * f2) * 2) = w;
  }
}

__global__ void __launch_bounds__(NTHR, 1) lstm_kernel(
    const float* __restrict__ x,
    const float* __restrict__ Wih,
    const float* __restrict__ Whh,
    const float* __restrict__ bih,
    const float* __restrict__ bhh,
    bf16* __restrict__ hbuf,       // [2][B_][H_] bf16
    u32* __restrict__ cnt,         // [4][4096]
    float* __restrict__ hf32,      // [B_][H_] final h fp32
    const bf16* __restrict__ xbf)  // [T][4][16][128] bf16 or nullptr
{
  __shared__ __align__(16) char smem[SMEM_SZ];

  const int tid = threadIdx.x;
  const int bid = blockIdx.x;
  const int rg = bid >> 5;          // 0..3
  const int jg = bid & 31;          // 0..31
  const int row0 = rg * 16;
  const int j0 = jg * 16;

  const int lane = tid & 63;
  const int wave = tid >> 6;
  const int fr = lane & 15;
  const int kg = lane >> 4;

  // ---- one-time: W slice -> register A-fragments ----
  bf16x8 wfrag[20];
  {
    const int G = (fr >> 2) * H_ + j0 + wave * 4 + (fr & 3);
    const float* sih = Wih + (size_t)G * F_;
    const float* shh = Whh + (size_t)G * H_;
    #pragma unroll
    for (int kk = 0; kk < 20; ++kk) {
      const float* s = (kk < 4) ? (sih + kk * 32 + kg * 8)
                                : (shh + (kk - 4) * 32 + kg * 8);
      float4 f0 = *(const float4*)s;
      float4 f1 = *(const float4*)(s + 4);
      bf16x8 w = { (bf16)f0.x, (bf16)f0.y, (bf16)f0.z, (bf16)f0.w,
                   (bf16)f1.x, (bf16)f1.y, (bf16)f1.z, (bf16)f1.w };
      wfrag[kk] = w;
    }
  }

  // per-lane cell (post-transpose): b = row0+fr, j = j0 + wave*4 + kg
  const int jcol = j0 + wave * 4 + kg;
  const float bi_ = bih[0 * H_ + jcol] + bhh[0 * H_ + jcol];
  const float bf_ = bih[1 * H_ + jcol] + bhh[1 * H_ + jcol];
  const float bg_ = bih[2 * H_ + jcol] + bhh[2 * H_ + jcol];
  const float bo_ = bih[3 * H_ + jcol] + bhh[3 * H_ + jcol];

  // data/unpack ids: thread (prow, pw) covers row prow, 4 chunks of 8 j
  const int prow = tid >> 4;        // 0..15
  const int pw = tid & 15;
  // f32-fallback x staging ids
  const int r0x = tid >> 5;
  const int c40 = tid & 31;
  const float* xp0 = x + (size_t)(row0 + r0x) * T_ * F_ + c40 * 4;
  const float* xp1 = x + (size_t)(row0 + r0x + 8) * T_ * F_ + c40 * 4;
  const int xw0 = r0x * ACT_STRIDE + ((8 * c40) ^ ((r0x & 7) << 4));
  const int xw1 = (r0x + 8) * ACT_STRIDE + ((8 * c40) ^ (((r0x + 8) & 7) << 4));
  // bf16 x staging ids (row = tid>>4, 16B seg = tid&15)
  const int xw = prow * ACT_STRIDE + ((pw * 16) ^ ((prow & 7) << 4));

  const char* bbase = smem + fr * ACT_STRIDE;
  const int bmask = (fr & 7) << 4;
  u32* cgrp = cnt + (rg << 12);

  float c_state = 0.f;

  for (int t = 0; t < T_; ++t) {
    // ---- stage x_t into LDS x-region [0,256)B per row ----
    if (xbf) {
      u32x4 xv = *(const u32x4*)((const char*)xbf
                  + ((size_t)t * 4 + rg) * 4096 + tid * 16);
      *(u32x4*)(smem + xw) = xv;
    } else {
      float4 xv0 = *(const float4*)(xp0 + (size_t)t * F_);
      float4 xv1 = *(const float4*)(xp1 + (size_t)t * F_);
      bf16x4 b0 = { (bf16)xv0.x, (bf16)xv0.y, (bf16)xv0.z, (bf16)xv0.w };
      bf16x4 b1 = { (bf16)xv1.x, (bf16)xv1.y, (bf16)xv1.z, (bf16)xv1.w };
      *(bf16x4*)(smem + xw0) = b0;
      *(bf16x4*)(smem + xw1) = b1;
    }
    __syncthreads();   // sync1: x ready; prior step's LDS reads all done

    // ---- issue counter poll; overlap x chunks 0,1 under the LLC RT ----
    u32 cv;
    const u32* cp = cgrp + t;
    asm volatile("global_load_dword %0, %1, off sc0 sc1" : "=v"(cv) : "v"(cp));

    f32x4 a0 = {0.f, 0.f, 0.f, 0.f}, a1 = {0.f, 0.f, 0.f, 0.f};
    f32x4 a2 = {0.f, 0.f, 0.f, 0.f}, a3 = {0.f, 0.f, 0.f, 0.f};
    {
      bf16x8 p0 = *(const bf16x8*)(bbase + ((0 * 64 + kg * 16) ^ bmask));
      a0 = __builtin_amdgcn_mfma_f32_16x16x32_bf16(wfrag[0], p0, a0, 0, 0, 0);
      bf16x8 p1 = *(const bf16x8*)(bbase + ((1 * 64 + kg * 16) ^ bmask));
      a1 = __builtin_amdgcn_mfma_f32_16x16x32_bf16(wfrag[1], p1, a1, 0, 0, 0);
    }
    {
      int guard = 0;
      for (;;) {
        asm volatile("s_waitcnt vmcnt(0)" ::: "memory");
        __builtin_amdgcn_sched_barrier(0);   // rule #18
        if (cv >= 128u) break;
        if (++guard > (1 << 22)) break;      // bail to wrong-answer, not hang
        asm volatile("global_load_dword %0, %1, off sc0 sc1" : "=v"(cv) : "v"(cp));
      }
    }

    // ---- data loads (once), x chunks 2,3 overlap the data RT ----
    u32x4 v0, v1, v2, v3;
    const char* hb = (const char*)hbuf + ((size_t)(t & 1) << 16)
                   + (size_t)(row0 + prow) * 1024 + pw * 16;
    asm volatile("global_load_dwordx4 %0, %1, off sc0 sc1"             : "=v"(v0) : "v"(hb));
    asm volatile("global_load_dwordx4 %0, %1, off offset:256 sc0 sc1"  : "=v"(v1) : "v"(hb));
    asm volatile("global_load_dwordx4 %0, %1, off offset:512 sc0 sc1"  : "=v"(v2) : "v"(hb));
    asm volatile("global_load_dwordx4 %0, %1, off offset:768 sc0 sc1"  : "=v"(v3) : "v"(hb));
    {
      bf16x8 p2 = *(const bf16x8*)(bbase + ((2 * 64 + kg * 16) ^ bmask));
      a2 = __builtin_amdgcn_mfma_f32_16x16x32_bf16(wfrag[2], p2, a2, 0, 0, 0);
      bf16x8 p3 = *(const bf16x8*)(bbase + ((3 * 64 + kg * 16) ^ bmask));
      a3 = __builtin_amdgcn_mfma_f32_16x16x32_bf16(wfrag[3], p3, a3, 0, 0, 0);
    }
    asm volatile("s_waitcnt vmcnt(0)" ::: "memory");
    __builtin_amdgcn_sched_barrier(0);

    // ---- unpack h -> act LDS h-region (16B per thread per chunk) ----
    {
      char* dst = smem + prow * ACT_STRIDE;
      const int swz = (prow & 7) << 4;
      *(u32x4*)(dst + ((256 + 0 * 256 + 16 * pw) ^ swz)) = v0;
      *(u32x4*)(dst + ((256 + 1 * 256 + 16 * pw) ^ swz)) = v1;
      *(u32x4*)(dst + ((256 + 2 * 256 + 16 * pw) ^ swz)) = v2;
      *(u32x4*)(dst + ((256 + 3 * 256 + 16 * pw) ^ swz)) = v3;
    }
    __syncthreads();   // sync2: h region ready

    // ---- h chunks kk = 4..19 across 4 accumulator chains ----
    #pragma unroll
    for (int kk = 4; kk < 20; kk += 4) {
      bf16x8 b0 = *(const bf16x8*)(bbase + (((kk + 0) * 64 + kg * 16) ^ bmask));
      a0 = __builtin_amdgcn_mfma_f32_16x16x32_bf16(wfrag[kk + 0], b0, a0, 0, 0, 0);
      bf16x8 b1 = *(const bf16x8*)(bbase + (((kk + 1) * 64 + kg * 16) ^ bmask));
      a1 = __builtin_amdgcn_mfma_f32_16x16x32_bf16(wfrag[kk + 1], b1, a1, 0, 0, 0);
      bf16x8 b2 = *(const bf16x8*)(bbase + (((kk + 2) * 64 + kg * 16) ^ bmask));
      a2 = __builtin_amdgcn_mfma_f32_16x16x32_bf16(wfrag[kk + 2], b2, a2, 0, 0, 0);
      bf16x8 b3 = *(const bf16x8*)(bbase + (((kk + 3) * 64 + kg * 16) ^ bmask));
      a3 = __builtin_amdgcn_mfma_f32_16x16x32_bf16(wfrag[kk + 3], b3, a3, 0, 0, 0);
    }
    f32x4 dsum = (a0 + a1) + (a2 + a3);

    // ---- 4x4 transpose across kg groups -> lane holds 4 gate types ----
    float d0 = dsum[0], d1 = dsum[1], d2 = dsum[2], d3 = dsum[3];
    float t0 = __shfl_xor((kg & 2) ? d0 : d2, 32, 64);
    float t1 = __shfl_xor((kg & 2) ? d1 : d3, 32, 64);
    float w0 = (kg & 2) ? t0 : d0;
    float w1 = (kg & 2) ? t1 : d1;
    float w2 = (kg & 2) ? d2 : t0;
    float w3 = (kg & 2) ? d3 : t1;
    float t2 = __shfl_xor((kg & 1) ? w0 : w1, 16, 64);
    float t3 = __shfl_xor((kg & 1) ? w2 : w3, 16, 64);
    float gi = (kg & 1) ? t2 : w0;
    float gf = (kg & 1) ? w1 : t2;
    float gg = (kg & 1) ? t3 : w2;
    float go = (kg & 1) ? w3 : t3;

    // ---- gate math + state update (1 cell per lane) ----
    float iv = sigm(gi + bi_);
    float fv = sigm(gf + bf_);
    float gv = tanh_f(gg + bg_);
    float ov = sigm(go + bo_);
    c_state = fv * c_state + iv * gv;
    float hv = ov * tanh_f(c_state);

    // ---- publish: store h slice, then per-wave counter increment ----
    {
      u32 hbits = bf16bits(hv);
      char* dstp = (char*)hbuf + ((size_t)((t + 1) & 1) << 16)
                 + (size_t)(row0 + fr) * 1024 + jcol * 2;
      asm volatile("global_store_short %0, %1, off sc0 sc1"
                   :: "v"(dstp), "v"(hbits) : "memory");
    }
    if (t == T_ - 1) hf32[(size_t)(row0 + fr) * H_ + jcol] = hv;
    asm volatile("s_waitcnt vmcnt(0)" ::: "memory");   // this wave's stores at LLC
    __builtin_amdgcn_sched_barrier(0);
    if (lane == 0) atomicAdd(cgrp + t + 1, 1u);        // device-scope RMW (m20)
  }
}

__global__ void __launch_bounds__(64) out_kernel(
    const float* __restrict__ h_f32,
    const float* __restrict__ Wout,
    const float* __restrict__ bout,
    float* __restrict__ out)
{
  int b = blockIdx.x;
  int lane = threadIdx.x;
  float a0 = 0.f, a1 = 0.f, a2 = 0.f, a3 = 0.f;
  for (int j = lane; j < H_; j += 64) {
    float hv = fmaxf(h_f32[(size_t)b * H_ + j], 0.f);
    a0 += hv * Wout[0 * H_ + j];
    a1 += hv * Wout[1 * H_ + j];
    a2 += hv * Wout[2 * H_ + j];
    a3 += hv * Wout[3 * H_ + j];
  }
  #pragma unroll
  for (int off = 32; off; off >>= 1) {
    a0 += __shfl_down(a0, off);
    a1 += __shfl_down(a1, off);
    a2 += __shfl_down(a2, off);
    a3 += __shfl_down(a3, off);
  }
  if (lane == 0) {
    out[b * 4 + 0] = a0 + bout[0];
    out[b * 4 + 1] = a1 + bout[1];
    out[b * 4 + 2] = a2 + bout[2];
    out[b * 4 + 3] = a3 + bout[3];
  }
}

extern "C" void kernel_launch(void* const* d_in, const int* in_sizes, int n_in,
                              void* d_out, int out_size, void* d_ws, size_t ws_size,
                              hipStream_t stream) {
  const float* x    = (const float*)d_in[0];
  const float* Wih  = (const float*)d_in[1];
  const float* Whh  = (const float*)d_in[2];
  const float* bih  = (const float*)d_in[3];
  const float* bhh  = (const float*)d_in[4];
  // d_in[5..8] = layer-1 weights: dead code in the reference, unused.
  const float* Wout = (const float*)d_in[9];
  const float* bout = (const float*)d_in[10];

  char* ws = (char*)d_ws;
  bf16*  hbuf = (bf16*)ws;                   // 131072 B
  float* hf32 = (float*)(ws + 131072);       // 131072 B
  u32*   cnt  = (u32*)(ws + 262144);         // 65536 B
  const size_t XBF_OFF = 393216;
  const size_t XBF_SZ = (size_t)T_ * 4 * 16 * 128 * 2;   // 33554432 B
  bf16* xbf = (ws_size >= XBF_OFF + XBF_SZ) ? (bf16*)(ws + XBF_OFF) : nullptr;

  hipLaunchKernelGGL(prep_kernel, dim3(NBLK), dim3(NTHR), 0, stream,
                     (u32*)hbuf, cnt);
  if (xbf)
    hipLaunchKernelGGL(xconv_kernel, dim3(64, 8), dim3(NTHR), 0, stream, x, xbf);

  void* args[] = { (void*)&x, (void*)&Wih, (void*)&Whh, (void*)&bih, (void*)&bhh,
                   (void*)&hbuf, (void*)&cnt, (void*)&hf32, (void*)&xbf };
  hipLaunchCooperativeKernel((void*)lstm_kernel, dim3(NBLK), dim3(NTHR),
                             args, 0, stream);

  hipLaunchKernelGGL(out_kernel, dim3(B_), dim3(64), 0, stream,
                     hf32, Wout, bout, (float*)d_out);
}